// Round 3
// baseline (209.794 us; speedup 1.0000x reference)
//
#include <hip/hip_runtime.h>

// DGCNN fused: 2x GCNConv + sort-pool(k=70) + folded MLP + sigmoid.
// K0: weff = lw1@lw2 (+beff) into d_ws.   K1: one block/graph, 512 thr, 3 blocks/CU.

#define NG      512
#define NPG     90
#define EPG     1440
#define IN_DIM  90
#define HD      64
#define KP      70
#define E_TOT   (NG*EPG)
#define NT      512

__global__ __launch_bounds__(256) void weff_fold(
    const float* __restrict__ lw1, const float* __restrict__ lb1,
    const float* __restrict__ lw2, const float* __restrict__ lb2,
    float* __restrict__ ws)
{
    int i = blockIdx.x*256 + threadIdx.x;
    if (i < KP*HD) {
        const float4* row = (const float4*)(lw1 + (size_t)i*HD);
        const float4* w   = (const float4*)lw2;
        float s = 0.f;
        #pragma unroll
        for (int j4 = 0; j4 < HD/4; ++j4) {
            float4 r = row[j4], v = w[j4];
            s += r.x*v.x + r.y*v.y + r.z*v.z + r.w*v.w;
        }
        ws[i] = s;
    } else if (i == KP*HD) {
        float s = lb2[0];
        for (int j = 0; j < HD; ++j) s += lb1[j]*lw2[j];
        ws[KP*HD] = s;
    }
}

__global__ __launch_bounds__(NT, 6) void dgcnn_fused(
    const float* __restrict__ x,     // [46080,90]
    const int*   __restrict__ ei,    // [2,E]
    const float* __restrict__ ew,    // [E]
    const float* __restrict__ W1,    // [90,64]
    const float* __restrict__ b1,    // [64]
    const float* __restrict__ W2,    // [64,64]
    const float* __restrict__ b2,    // [64]
    const float* __restrict__ weff,  // [4481] from K0
    float* __restrict__ out,         // [512]
    float* __restrict__ xtrain)      // [46080,64]
{
    __shared__ float sB[NPG*HD];           // xw / hw2
    __shared__ float sC[NPG*HD];           // W1 stage -> h1(relu) -> h2
    __shared__ float s_dinv[NPG];          // deg -> dinv (reused)
    __shared__ int   s_cursor[NPG];        // indeg -> cursor (reused)
    __shared__ int   s_rowstart[NPG+1];
    __shared__ unsigned s_epack[EPG];      // norm (hi 25 bits) | src (low 7)
    __shared__ int   s_ranknode[KP];
    __shared__ float s_red[8];

    const int g = blockIdx.x;
    const int t = threadIdx.x;
    const int j = t & 63;
    const int grp = t >> 6;
    const int ebase = g*EPG;
    const int nbase = g*NPG;

    // ---- A: init ----
    if (t < NPG) { s_dinv[t] = 1.0f; s_cursor[t] = 0; }
    __syncthreads();

    // ---- B: edge loads (held in regs) + degree/indegree; stage W1 -> sC ----
    int   e_s[3], e_d[3];
    float e_w[3];
    #pragma unroll
    for (int m = 0; m < 3; ++m) {
        int e = t + m*NT;
        if (e < EPG) {
            e_s[m] = ei[ebase + e] - nbase;
            e_d[m] = ei[E_TOT + ebase + e] - nbase;
            e_w[m] = ew[ebase + e];
            atomicAdd(&s_dinv[e_d[m]], e_w[m]);
            atomicAdd(&s_cursor[e_d[m]], 1);
        }
    }
    for (int i4 = t; i4 < IN_DIM*HD/4; i4 += NT)
        ((float4*)sC)[i4] = ((const float4*)W1)[i4];
    __syncthreads();

    // ---- C1: dinv + prefix scan of indegree ----
    if (t < NPG) s_dinv[t] = rsqrtf(fmaxf(s_dinv[t], 1e-12f));
    if (t <= NPG) {
        int acc = 0;
        for (int i = 0; i < t; ++i) acc += s_cursor[i];
        s_rowstart[t] = acc;
    }
    __syncthreads();
    // ---- C2: cursor init (reuse s_cursor) ----
    if (t < NPG) s_cursor[t] = s_rowstart[t];
    __syncthreads();

    // ---- D: CSR fill, packed u32 {norm[31:7], src[6:0]} ----
    #pragma unroll
    for (int m = 0; m < 3; ++m) {
        int e = t + m*NT;
        if (e < EPG) {
            int s = e_s[m], d = e_d[m];
            float nrm = s_dinv[s] * e_w[m] * s_dinv[d];
            int pos = atomicAdd(&s_cursor[d], 1);
            s_epack[pos] = (__float_as_uint(nrm) & ~127u) | (unsigned)s;
        }
    }
    __syncthreads();

    // ---- E: layer1 matmul sB = x_g @ W1, 4 rows/(wave,it) ----
    const float* xg = x + (size_t)nbase * IN_DIM;
    for (int it = 0; it < 3; ++it) {
        int r0 = it*32 + grp*4;
        int rr0 = min(r0+0, NPG-1), rr1 = min(r0+1, NPG-1);
        int rr2 = min(r0+2, NPG-1), rr3 = min(r0+3, NPG-1);
        const float2* xp0 = (const float2*)(xg + rr0*IN_DIM);
        const float2* xp1 = (const float2*)(xg + rr1*IN_DIM);
        const float2* xp2 = (const float2*)(xg + rr2*IN_DIM);
        const float2* xp3 = (const float2*)(xg + rr3*IN_DIM);
        float a0 = 0.f, a1 = 0.f, a2 = 0.f, a3 = 0.f;
        #pragma unroll 9
        for (int kh = 0; kh < IN_DIM/2; ++kh) {
            float w0 = sC[(2*kh)*HD + j];
            float w1 = sC[(2*kh+1)*HD + j];
            float2 v0 = xp0[kh], v1 = xp1[kh], v2 = xp2[kh], v3 = xp3[kh];
            a0 += v0.x*w0 + v0.y*w1;
            a1 += v1.x*w0 + v1.y*w1;
            a2 += v2.x*w0 + v2.y*w1;
            a3 += v3.x*w0 + v3.y*w1;
        }
        if (r0+0 < NPG) sB[(r0+0)*HD + j] = a0;
        if (r0+1 < NPG) sB[(r0+1)*HD + j] = a1;
        if (r0+2 < NPG) sB[(r0+2)*HD + j] = a2;
        if (r0+3 < NPG) sB[(r0+3)*HD + j] = a3;
    }
    __syncthreads();

    // ---- F: scatter1 + bias + xtrain store + relu -> sC (overwrites W1) ----
    float* xt = xtrain + (size_t)nbase * HD;
    for (int o = t; o < NPG*HD; o += NT) {
        int d = o >> 6, c = o & 63;
        float dv = s_dinv[d];
        float a = dv*dv*sB[o];
        int p0 = s_rowstart[d], p1 = s_rowstart[d+1];
        for (int p = p0; p < p1; ++p) {
            unsigned u = s_epack[p];
            a += __uint_as_float(u & ~127u) * sB[(int)(u & 127u)*HD + c];
        }
        a += b1[c];
        xt[o] = a;
        sC[o] = fmaxf(a, 0.f);
    }
    __syncthreads();

    // ---- H: layer2 matmul sB = relu(h1) @ W2 (W2 from global, L1-hot) ----
    for (int it = 0; it < 3; ++it) {
        int r0 = it*32 + grp*4;
        int rr0 = min(r0+0, NPG-1), rr1 = min(r0+1, NPG-1);
        int rr2 = min(r0+2, NPG-1), rr3 = min(r0+3, NPG-1);
        float a0 = 0.f, a1 = 0.f, a2 = 0.f, a3 = 0.f;
        #pragma unroll 4
        for (int k4 = 0; k4 < HD/4; ++k4) {
            int k = k4*4;
            float4 h0 = *(const float4*)&sC[rr0*HD + k];
            float4 h1 = *(const float4*)&sC[rr1*HD + k];
            float4 h2 = *(const float4*)&sC[rr2*HD + k];
            float4 h3 = *(const float4*)&sC[rr3*HD + k];
            float w0 = W2[(k+0)*HD + j];
            float w1 = W2[(k+1)*HD + j];
            float w2 = W2[(k+2)*HD + j];
            float w3 = W2[(k+3)*HD + j];
            a0 += h0.x*w0 + h0.y*w1 + h0.z*w2 + h0.w*w3;
            a1 += h1.x*w0 + h1.y*w1 + h1.z*w2 + h1.w*w3;
            a2 += h2.x*w0 + h2.y*w1 + h2.z*w2 + h2.w*w3;
            a3 += h3.x*w0 + h3.y*w1 + h3.z*w2 + h3.w*w3;
        }
        if (r0+0 < NPG) sB[(r0+0)*HD + j] = a0;
        if (r0+1 < NPG) sB[(r0+1)*HD + j] = a1;
        if (r0+2 < NPG) sB[(r0+2)*HD + j] = a2;
        if (r0+3 < NPG) sB[(r0+3)*HD + j] = a3;
    }
    __syncthreads();

    // ---- I: scatter2 -> sC ----
    for (int o = t; o < NPG*HD; o += NT) {
        int d = o >> 6, c = o & 63;
        float dv = s_dinv[d];
        float a = dv*dv*sB[o];
        int p0 = s_rowstart[d], p1 = s_rowstart[d+1];
        for (int p = p0; p < p1; ++p) {
            unsigned u = s_epack[p];
            a += __uint_as_float(u & ~127u) * sB[(int)(u & 127u)*HD + c];
        }
        sC[o] = a + b2[c];
    }
    __syncthreads();

    // ---- J: sort-pool rank (stable descending on channel 63) ----
    if (t < NPG) {
        float vi = sC[t*HD + (HD-1)];
        int rank = 0;
        for (int jj = 0; jj < NPG; ++jj) {
            float vj = sC[jj*HD + (HD-1)];
            rank += (vj > vi) || (vj == vi && jj < t);
        }
        if (rank < KP) s_ranknode[rank] = t;
    }
    __syncthreads();

    // ---- K: folded MLP = dot(pooled, weff) + beff -> sigmoid ----
    float part = 0.f;
    #pragma unroll
    for (int m = 0; m < 9; ++m) {
        int i = t + m*NT;
        if (i < KP*HD) {
            int k = i >> 6, c = i & 63;               // k uniform per 64-lane group
            part += weff[i] * sC[s_ranknode[k]*HD + c];
        }
    }
    #pragma unroll
    for (int off = 32; off > 0; off >>= 1) part += __shfl_down(part, off, 64);
    if (j == 0) s_red[grp] = part;
    __syncthreads();
    if (t == 0) {
        float zz = weff[KP*HD];
        #pragma unroll
        for (int m = 0; m < 8; ++m) zz += s_red[m];
        out[g] = 1.0f / (1.0f + expf(-zz));
    }
}

extern "C" void kernel_launch(void* const* d_in, const int* in_sizes, int n_in,
                              void* d_out, int out_size, void* d_ws, size_t ws_size,
                              hipStream_t stream) {
    const float* x   = (const float*)d_in[0];
    const int*   ei  = (const int*)  d_in[1];
    const float* ew  = (const float*)d_in[2];
    const float* W1  = (const float*)d_in[4];
    const float* b1  = (const float*)d_in[5];
    const float* W2  = (const float*)d_in[6];
    const float* b2  = (const float*)d_in[7];
    const float* lw1 = (const float*)d_in[8];
    const float* lb1 = (const float*)d_in[9];
    const float* lw2 = (const float*)d_in[10];
    const float* lb2 = (const float*)d_in[11];

    float* ws     = (float*)d_ws;         // weff[4480] + beff
    float* out    = (float*)d_out;        // [512]
    float* xtrain = out + NG;             // [46080*64]

    weff_fold<<<(KP*HD + 256)/256, 256, 0, stream>>>(lw1, lb1, lw2, lb2, ws);
    dgcnn_fused<<<NG, NT, 0, stream>>>(x, ei, ew, W1, b1, W2, b2,
                                       ws, out, xtrain);
}

// Round 5
// 182.317 us; speedup vs baseline: 1.1507x; 1.1507x over previous
//
#include <hip/hip_runtime.h>

// DGCNN fused: 2x GCNConv + sort-pool(k=70) + folded MLP + sigmoid.
// K0: weff = lw1@lw2 (+beff) into d_ws.   K1: one block/graph, 512 thr.
// LDS ~53.9 KB -> 3 blocks/CU; launch_bounds(512,4) to avoid spills (R3 lesson).

#define NG      512
#define NPG     90
#define EPG     1440
#define IN_DIM  90
#define HD      64
#define KP      70
#define E_TOT   (NG*EPG)
#define NT      512

__global__ __launch_bounds__(256) void weff_fold(
    const float* __restrict__ lw1, const float* __restrict__ lb1,
    const float* __restrict__ lw2, const float* __restrict__ lb2,
    float* __restrict__ ws)
{
    int i = blockIdx.x*256 + threadIdx.x;
    if (i < KP*HD) {
        const float4* row = (const float4*)(lw1 + (size_t)i*HD);
        const float4* w   = (const float4*)lw2;
        float s = 0.f;
        #pragma unroll
        for (int j4 = 0; j4 < HD/4; ++j4) {
            float4 r = row[j4], v = w[j4];
            s += r.x*v.x + r.y*v.y + r.z*v.z + r.w*v.w;
        }
        ws[i] = s;
    } else if (i == KP*HD) {
        float s = lb2[0];
        for (int j = 0; j < HD; ++j) s += lb1[j]*lw2[j];
        ws[KP*HD] = s;
    }
}

__global__ __launch_bounds__(NT, 4) void dgcnn_fused(
    const float* __restrict__ x,     // [46080,90]
    const int*   __restrict__ ei,    // [2,E]
    const float* __restrict__ ew,    // [E]
    const float* __restrict__ W1,    // [90,64]
    const float* __restrict__ b1,    // [64]
    const float* __restrict__ W2,    // [64,64]
    const float* __restrict__ b2,    // [64]
    const float* __restrict__ weff,  // [4481] from K0
    float* __restrict__ out,         // [512]
    float* __restrict__ xtrain)      // [46080,64]
{
    __shared__ float sB[NPG*HD];           // xw / hw2
    __shared__ float sC[NPG*HD];           // W1 stage -> h1(relu) -> h2
    __shared__ float s_dinv[NPG];          // deg -> dinv (in place)
    __shared__ int   s_indeg[NPG];
    __shared__ int   s_cursor[NPG];
    __shared__ int   s_rowstart[NPG+1];
    __shared__ unsigned s_epack[EPG];      // norm (hi 25 bits) | src (low 7)
    __shared__ int   s_ranknode[KP];
    __shared__ float s_red[8];

    const int g = blockIdx.x;
    const int t = threadIdx.x;
    const int j = t & 63;
    const int grp = t >> 6;
    const int ebase = g*EPG;
    const int nbase = g*NPG;

    // ---- A: init ----
    if (t < NPG) { s_dinv[t] = 1.0f; s_indeg[t] = 0; }
    __syncthreads();

    // ---- B: degree + indegree (atomics); stage W1 -> sC ----
    for (int e = t; e < EPG; e += NT) {
        int d = ei[E_TOT + ebase + e] - nbase;
        float w = ew[ebase + e];
        atomicAdd(&s_dinv[d], w);
        atomicAdd(&s_indeg[d], 1);
    }
    for (int i4 = t; i4 < IN_DIM*HD/4; i4 += NT)
        ((float4*)sC)[i4] = ((const float4*)W1)[i4];
    __syncthreads();

    // ---- C: dinv in place + prefix scan of indegree + cursor init ----
    if (t < NPG) s_dinv[t] = rsqrtf(fmaxf(s_dinv[t], 1e-12f));
    if (t <= NPG) {
        int acc = 0;
        for (int i = 0; i < t; ++i) acc += s_indeg[i];
        s_rowstart[t] = acc;
        if (t < NPG) s_cursor[t] = acc;
    }
    __syncthreads();

    // ---- D: CSR fill, packed u32 {norm[31:7], src[6:0]} (ei/ew L1-hot) ----
    for (int e = t; e < EPG; e += NT) {
        int s = ei[ebase + e] - nbase;
        int d = ei[E_TOT + ebase + e] - nbase;
        float nrm = s_dinv[s] * ew[ebase + e] * s_dinv[d];
        int pos = atomicAdd(&s_cursor[d], 1);
        s_epack[pos] = (__float_as_uint(nrm) & ~127u) | (unsigned)s;
    }
    __syncthreads();

    // ---- E: layer1 matmul sB = x_g @ W1, 4 rows/(wave,it) ----
    const float* xg = x + (size_t)nbase * IN_DIM;
    for (int it = 0; it < 3; ++it) {
        int r0 = it*32 + grp*4;
        int rr0 = min(r0+0, NPG-1), rr1 = min(r0+1, NPG-1);
        int rr2 = min(r0+2, NPG-1), rr3 = min(r0+3, NPG-1);
        const float2* xp0 = (const float2*)(xg + rr0*IN_DIM);
        const float2* xp1 = (const float2*)(xg + rr1*IN_DIM);
        const float2* xp2 = (const float2*)(xg + rr2*IN_DIM);
        const float2* xp3 = (const float2*)(xg + rr3*IN_DIM);
        float a0 = 0.f, a1 = 0.f, a2 = 0.f, a3 = 0.f;
        #pragma unroll 9
        for (int kh = 0; kh < IN_DIM/2; ++kh) {
            float w0 = sC[(2*kh)*HD + j];
            float w1 = sC[(2*kh+1)*HD + j];
            float2 v0 = xp0[kh], v1 = xp1[kh], v2 = xp2[kh], v3 = xp3[kh];
            a0 += v0.x*w0 + v0.y*w1;
            a1 += v1.x*w0 + v1.y*w1;
            a2 += v2.x*w0 + v2.y*w1;
            a3 += v3.x*w0 + v3.y*w1;
        }
        if (r0+0 < NPG) sB[(r0+0)*HD + j] = a0;
        if (r0+1 < NPG) sB[(r0+1)*HD + j] = a1;
        if (r0+2 < NPG) sB[(r0+2)*HD + j] = a2;
        if (r0+3 < NPG) sB[(r0+3)*HD + j] = a3;
    }
    __syncthreads();

    // ---- F: scatter1 + bias + xtrain store + relu -> sC ----
    float* xt = xtrain + (size_t)nbase * HD;
    for (int o = t; o < NPG*HD; o += NT) {
        int d = o >> 6, c = o & 63;
        float dv = s_dinv[d];
        float a = dv*dv*sB[o];
        int p0 = s_rowstart[d], p1 = s_rowstart[d+1];
        for (int p = p0; p < p1; ++p) {
            unsigned u = s_epack[p];
            a += __uint_as_float(u & ~127u) * sB[(int)(u & 127u)*HD + c];
        }
        a += b1[c];
        xt[o] = a;
        sC[o] = fmaxf(a, 0.f);
    }
    __syncthreads();

    // ---- H: layer2 matmul sB = relu(h1) @ W2 (W2 from global, L1-hot) ----
    for (int it = 0; it < 3; ++it) {
        int r0 = it*32 + grp*4;
        int rr0 = min(r0+0, NPG-1), rr1 = min(r0+1, NPG-1);
        int rr2 = min(r0+2, NPG-1), rr3 = min(r0+3, NPG-1);
        float a0 = 0.f, a1 = 0.f, a2 = 0.f, a3 = 0.f;
        #pragma unroll 4
        for (int k4 = 0; k4 < HD/4; ++k4) {
            int k = k4*4;
            float4 h0 = *(const float4*)&sC[rr0*HD + k];
            float4 h1 = *(const float4*)&sC[rr1*HD + k];
            float4 h2 = *(const float4*)&sC[rr2*HD + k];
            float4 h3 = *(const float4*)&sC[rr3*HD + k];
            float w0 = W2[(k+0)*HD + j];
            float w1 = W2[(k+1)*HD + j];
            float w2 = W2[(k+2)*HD + j];
            float w3 = W2[(k+3)*HD + j];
            a0 += h0.x*w0 + h0.y*w1 + h0.z*w2 + h0.w*w3;
            a1 += h1.x*w0 + h1.y*w1 + h1.z*w2 + h1.w*w3;
            a2 += h2.x*w0 + h2.y*w1 + h2.z*w2 + h2.w*w3;
            a3 += h3.x*w0 + h3.y*w1 + h3.z*w2 + h3.w*w3;
        }
        if (r0+0 < NPG) sB[(r0+0)*HD + j] = a0;
        if (r0+1 < NPG) sB[(r0+1)*HD + j] = a1;
        if (r0+2 < NPG) sB[(r0+2)*HD + j] = a2;
        if (r0+3 < NPG) sB[(r0+3)*HD + j] = a3;
    }
    __syncthreads();

    // ---- I: scatter2 -> sC ----
    for (int o = t; o < NPG*HD; o += NT) {
        int d = o >> 6, c = o & 63;
        float dv = s_dinv[d];
        float a = dv*dv*sB[o];
        int p0 = s_rowstart[d], p1 = s_rowstart[d+1];
        for (int p = p0; p < p1; ++p) {
            unsigned u = s_epack[p];
            a += __uint_as_float(u & ~127u) * sB[(int)(u & 127u)*HD + c];
        }
        sC[o] = a + b2[c];
    }
    __syncthreads();

    // ---- J: sort-pool rank (stable descending on channel 63) ----
    if (t < NPG) {
        float vi = sC[t*HD + (HD-1)];
        int rank = 0;
        for (int jj = 0; jj < NPG; ++jj) {
            float vj = sC[jj*HD + (HD-1)];
            rank += (vj > vi) || (vj == vi && jj < t);
        }
        if (rank < KP) s_ranknode[rank] = t;
    }
    __syncthreads();

    // ---- K: folded MLP = dot(pooled, weff) + beff -> sigmoid ----
    float part = 0.f;
    #pragma unroll
    for (int m = 0; m < 9; ++m) {
        int i = t + m*NT;
        if (i < KP*HD) {
            int k = i >> 6, c = i & 63;               // k uniform per 64-lane group
            part += weff[i] * sC[s_ranknode[k]*HD + c];
        }
    }
    #pragma unroll
    for (int off = 32; off > 0; off >>= 1) part += __shfl_down(part, off, 64);
    if (j == 0) s_red[grp] = part;
    __syncthreads();
    if (t == 0) {
        float zz = weff[KP*HD];
        #pragma unroll
        for (int m = 0; m < 8; ++m) zz += s_red[m];
        out[g] = 1.0f / (1.0f + expf(-zz));
    }
}

extern "C" void kernel_launch(void* const* d_in, const int* in_sizes, int n_in,
                              void* d_out, int out_size, void* d_ws, size_t ws_size,
                              hipStream_t stream) {
    const float* x   = (const float*)d_in[0];
    const int*   ei  = (const int*)  d_in[1];
    const float* ew  = (const float*)d_in[2];
    const float* W1  = (const float*)d_in[4];
    const float* b1  = (const float*)d_in[5];
    const float* W2  = (const float*)d_in[6];
    const float* b2  = (const float*)d_in[7];
    const float* lw1 = (const float*)d_in[8];
    const float* lb1 = (const float*)d_in[9];
    const float* lw2 = (const float*)d_in[10];
    const float* lb2 = (const float*)d_in[11];

    float* ws     = (float*)d_ws;         // weff[4480] + beff
    float* out    = (float*)d_out;        // [512]
    float* xtrain = out + NG;             // [46080*64]

    weff_fold<<<(KP*HD + 256)/256, 256, 0, stream>>>(lw1, lb1, lw2, lb2, ws);
    dgcnn_fused<<<NG, NT, 0, stream>>>(x, ei, ew, W1, b1, W2, b2,
                                       ws, out, xtrain);
}